// Round 4
// baseline (155.417 us; speedup 1.0000x reference)
//
#include <hip/hip_runtime.h>

#define B 8
#define CCH 3
#define HH 512
#define WW 512
#define WIN 21
#define PAD 10
#define TSX 32
#define TSY 32
#define PTY 52                // TSY + 2*PAD padded rows
#define TROW 56               // tile row stride in floats (16B-aligned)
#define HROW 54               // hs_t rows per column; stride 108 dwords == 12 mod 32
                              // -> 8 consecutive lanes' b128 reads sweep all 32 banks

// Kernel 1: one block = one (tile, channel, batch). Computes this batch's
// w and w*p for every pixel of the tile, atomically accumulates into ws.
__global__ __launch_bounds__(256) void nlm_accum_kernel(const float* __restrict__ noisy,
                                                        float2* __restrict__ ws) {
    __shared__ float  tile[PTY][TROW];    // 52 x 56 floats (11648 B)
    __shared__ float2 hs_t[TSX][HROW];    // [col][row] (s1,s2) (13824 B)

    const int tid = threadIdx.x;
    const int x0 = blockIdx.x * TSX;
    const int y0 = blockIdx.y * TSY;
    const int ch = blockIdx.z % CCH;
    const int b  = blockIdx.z / CCH;

    const float* src = noisy + (size_t)(b * CCH + ch) * (HH * WW);

    // ---- stage reflect-padded 52x52 tile (float4 global + ds_write_b128) ----
    for (int s = tid; s < PTY * 13; s += 256) {
        int r  = s / 13;
        int c4 = s - r * 13;
        int gy = y0 + r - PAD;
        gy = (gy < 0) ? -gy : ((gy >= HH) ? (2 * (HH - 1) - gy) : gy);
        int gxs = x0 + (c4 << 2) - PAD;
        float4 v;
        if (gxs >= 0 && gxs <= WW - 4) {
            v = *(const float4*)(src + gy * WW + gxs);
        } else {
            float tmp[4];
            #pragma unroll
            for (int t = 0; t < 4; ++t) {
                int gx = gxs + t;
                gx = (gx < 0) ? -gx : ((gx >= WW) ? (2 * (WW - 1) - gx) : gx);
                tmp[t] = src[gy * WW + gx];
            }
            v = make_float4(tmp[0], tmp[1], tmp[2], tmp[3]);
        }
        *(float4*)&tile[r][c4 << 2] = v;
    }
    __syncthreads();

    // ---- horizontal box sums: 52 rows x 4 segments of 8 output cols ----
    // unit reads 28 floats (7 x b128), emits 8 (s1,s2) pairs
    if (tid < PTY * 4) {
        int r   = tid >> 2;
        int cx0 = (tid & 3) << 3;         // 0,8,16,24
        float v[28];
        #pragma unroll
        for (int q = 0; q < 7; ++q)
            *(float4*)&v[q * 4] = *(const float4*)&tile[r][cx0 + q * 4];
        float s1 = 0.f, s2 = 0.f;
        #pragma unroll
        for (int k = 0; k < WIN; ++k) { s1 += v[k]; s2 = fmaf(v[k], v[k], s2); }
        hs_t[cx0][r] = make_float2(s1, s2);
        #pragma unroll
        for (int j = 1; j < 8; ++j) {
            float vo = v[j - 1], vn = v[j + WIN - 1];
            s1 += vn - vo;
            s2 += vn * vn - vo * vo;
            hs_t[cx0 + j][r] = make_float2(s1, s2);
        }
    }
    __syncthreads();

    // ---- vertical sliding sums: 4 output rows per thread ----
    const int tx  = tid & 31;
    const int ty0 = (tid >> 5) << 2;      // 0,4,...,28

    // stream 12 b128 reads covering hs rows ty0 .. ty0+23; keep q0,q1,q10,q11
    float4 q0 = *(const float4*)&hs_t[tx][ty0];           // rows +0,+1
    float4 q1 = *(const float4*)&hs_t[tx][ty0 + 2];       // rows +2,+3
    float vs1 = q0.x + q0.z + q1.x + q1.z;
    float vs2 = q0.y + q0.w + q1.y + q1.w;
    #pragma unroll
    for (int k = 2; k < 10; ++k) {
        float4 q = *(const float4*)&hs_t[tx][ty0 + 2 * k];
        vs1 += q.x + q.z;
        vs2 += q.y + q.w;
    }
    float4 q10 = *(const float4*)&hs_t[tx][ty0 + 20];     // rows +20,+21
    float4 q11 = *(const float4*)&hs_t[tx][ty0 + 22];     // rows +22,+23
    vs1 += q10.x;
    vs2 += q10.y;

    float wv[4], wp[4];
    {
        float a = tile[ty0 + PAD][tx + PAD];
        float p = tile[ty0][tx];
        float dd = vs2 - 2.f * a * vs1 + 441.f * a * a;
        float w = __expf(dd * (-100.f / 441.f));
        wv[0] = w; wp[0] = w * p;
    }
    vs1 += q10.z - q0.x;  vs2 += q10.w - q0.y;            // slide to +1
    {
        float a = tile[ty0 + 1 + PAD][tx + PAD];
        float p = tile[ty0 + 1][tx];
        float dd = vs2 - 2.f * a * vs1 + 441.f * a * a;
        float w = __expf(dd * (-100.f / 441.f));
        wv[1] = w; wp[1] = w * p;
    }
    vs1 += q11.x - q0.z;  vs2 += q11.y - q0.w;            // slide to +2
    {
        float a = tile[ty0 + 2 + PAD][tx + PAD];
        float p = tile[ty0 + 2][tx];
        float dd = vs2 - 2.f * a * vs1 + 441.f * a * a;
        float w = __expf(dd * (-100.f / 441.f));
        wv[2] = w; wp[2] = w * p;
    }
    vs1 += q11.z - q1.x;  vs2 += q11.w - q1.y;            // slide to +3
    {
        float a = tile[ty0 + 3 + PAD][tx + PAD];
        float p = tile[ty0 + 3][tx];
        float dd = vs2 - 2.f * a * vs1 + 441.f * a * a;
        float w = __expf(dd * (-100.f / 441.f));
        wv[3] = w; wp[3] = w * p;
    }

    // ---- accumulate into workspace ----
    #pragma unroll
    for (int i = 0; i < 4; ++i) {
        int y = y0 + ty0 + i;
        int x = x0 + tx;
        float2* dst = ws + ((size_t)(ch * HH + y) * WW + x);
        atomicAdd(&dst->x, wp[i]);
        atomicAdd(&dst->y, wv[i]);
    }
}

// Kernel 2: normalize and broadcast to all 8 batch slices.
__global__ __launch_bounds__(256) void nlm_finalize_kernel(const float2* __restrict__ ws,
                                                           float* __restrict__ out) {
    int i = blockIdx.x * 256 + threadIdx.x;   // over CCH*HH*WW
    float2 nd = ws[i];
    float v = nd.x / (nd.y + 1e-10f);
    v = v < 0.f ? 0.f : (v > 1.f ? 1.f : v);
    #pragma unroll
    for (int b = 0; b < B; ++b) {
        out[(size_t)b * (CCH * HH * WW) + i] = v;
    }
}

extern "C" void kernel_launch(void* const* d_in, const int* in_sizes, int n_in,
                              void* d_out, int out_size, void* d_ws, size_t ws_size,
                              hipStream_t stream) {
    const float* noisy = (const float*)d_in[0];
    float* out = (float*)d_out;
    float2* ws = (float2*)d_ws;

    hipMemsetAsync(d_ws, 0, (size_t)CCH * HH * WW * sizeof(float2), stream);

    dim3 grid1(WW / TSX, HH / TSY, CCH * B);
    nlm_accum_kernel<<<grid1, dim3(256), 0, stream>>>(noisy, ws);

    dim3 grid2((CCH * HH * WW) / 256);
    nlm_finalize_kernel<<<grid2, dim3(256), 0, stream>>>(ws, out);
}

// Round 5
// 88.938 us; speedup vs baseline: 1.7475x; 1.7475x over previous
//
#include <hip/hip_runtime.h>

#define B 8
#define CCH 3
#define HH 512
#define WW 512
#define WIN 21
#define PAD 10
#define TSX 32
#define TSY 32
#define PTY 52                 // TSY + 2*PAD rows staged
#define TROW 60                // tile row stride (dwords): 28r+4c sweeps all 32 banks
#define HSH 53                 // hs rows per column (odd -> 2-way max on both phases)
#define NSLOT 676              // 52 rows x 13 float4 groups

__global__ __launch_bounds__(256, 3) void nlm_fused_kernel(const float* __restrict__ noisy,
                                                           float* __restrict__ out) {
    __shared__ float  tile[PTY][TROW];     // 12480 B
    __shared__ float2 hs_t[TSX][HSH];      // [col][row] (s1,s2), 13568 B

    const int tid = threadIdx.x;
    const int x0 = blockIdx.x * TSX;
    const int y0 = blockIdx.y * TSY;
    const int ch = blockIdx.z;

    // ---- precompute staging slots (addresses batch-invariant) ----
    int   rowbase[3], gxs[3];
    float* ldsp[3];
    bool  valid[3], edge[3];
    #pragma unroll
    for (int k = 0; k < 3; ++k) {
        int s = tid + 256 * k;
        valid[k] = (s < NSLOT);
        int ss = valid[k] ? s : 0;
        int r  = ss / 13;
        int c4 = ss - r * 13;
        int gy = y0 + r - PAD;
        gy = (gy < 0) ? -gy : ((gy >= HH) ? (2 * (HH - 1) - gy) : gy);
        int gx = x0 + (c4 << 2) - PAD;
        rowbase[k] = gy * WW;
        gxs[k]     = gx;
        edge[k]    = (gx < 0) || (gx > WW - 4);
        ldsp[k]    = &tile[r][c4 << 2];
    }

    const float* src0 = noisy + (size_t)ch * (HH * WW);
    float4 pre[3];
    // prefetch batch 0
    #pragma unroll
    for (int k = 0; k < 3; ++k) {
        if (valid[k]) {
            if (!edge[k]) {
                pre[k] = *(const float4*)(src0 + rowbase[k] + gxs[k]);
            } else {
                float tmp[4];
                #pragma unroll
                for (int t = 0; t < 4; ++t) {
                    int gx = gxs[k] + t;
                    gx = (gx < 0) ? -gx : ((gx >= WW) ? (2 * (WW - 1) - gx) : gx);
                    tmp[t] = src0[rowbase[k] + gx];
                }
                pre[k] = make_float4(tmp[0], tmp[1], tmp[2], tmp[3]);
            }
        }
    }

    float num[4] = {0.f, 0.f, 0.f, 0.f};
    float den[4] = {0.f, 0.f, 0.f, 0.f};

    const int tx  = tid & 31;
    const int ty0 = (tid >> 5) << 2;       // 4 consecutive output rows / thread

    for (int b = 0; b < B; ++b) {
        __syncthreads();                   // all reads of previous tile done
        #pragma unroll
        for (int k = 0; k < 3; ++k)
            if (valid[k]) *(float4*)ldsp[k] = pre[k];
        __syncthreads();

        // issue next batch's global loads now; latency hides behind compute
        if (b < B - 1) {
            const float* srcn = noisy + (size_t)((b + 1) * CCH + ch) * (HH * WW);
            #pragma unroll
            for (int k = 0; k < 3; ++k) {
                if (valid[k]) {
                    if (!edge[k]) {
                        pre[k] = *(const float4*)(srcn + rowbase[k] + gxs[k]);
                    } else {
                        float tmp[4];
                        #pragma unroll
                        for (int t = 0; t < 4; ++t) {
                            int gx = gxs[k] + t;
                            gx = (gx < 0) ? -gx : ((gx >= WW) ? (2 * (WW - 1) - gx) : gx);
                            tmp[t] = srcn[rowbase[k] + gx];
                        }
                        pre[k] = make_float4(tmp[0], tmp[1], tmp[2], tmp[3]);
                    }
                }
            }
        }

        // ---- horizontal box sums: 52 rows x 4 segments of 8 output cols ----
        if (tid < PTY * 4) {
            int r   = tid >> 2;
            int cx0 = (tid & 3) << 3;      // 0,8,16,24
            float v[28];
            #pragma unroll
            for (int q = 0; q < 7; ++q)
                *(float4*)&v[q * 4] = *(const float4*)&tile[r][cx0 + (q << 2)];
            float s1 = 0.f, s2 = 0.f;
            #pragma unroll
            for (int k = 0; k <= 20; ++k) { s1 += v[k]; s2 = fmaf(v[k], v[k], s2); }
            hs_t[cx0][r] = make_float2(s1, s2);
            #pragma unroll
            for (int j = 1; j < 8; ++j) {
                float vo = v[j - 1], vn = v[j + 20];
                s1 += vn - vo;
                s2 += vn * vn - vo * vo;
                hs_t[cx0 + j][r] = make_float2(s1, s2);
            }
        }
        __syncthreads();

        // ---- vertical sliding sums: 4 output rows per thread ----
        float2 h0 = hs_t[tx][ty0];
        float2 h1 = hs_t[tx][ty0 + 1];
        float2 h2 = hs_t[tx][ty0 + 2];
        float vs1 = h0.x + h1.x + h2.x;
        float vs2 = h0.y + h1.y + h2.y;
        #pragma unroll
        for (int k = 3; k <= 20; ++k) {
            float2 h = hs_t[tx][ty0 + k];
            vs1 += h.x;
            vs2 += h.y;
        }
        const float kE = (-100.0f / 441.0f) * 1.44269504088896f;  // fold 1/h^2/n/ln2
        {
            float a = tile[ty0 + PAD][tx + PAD];
            float p = tile[ty0][tx];
            float dd = fmaf(a, fmaf(441.f, a, -2.f * vs1), vs2);
            float w = exp2f(dd * kE);
            num[0] += w * p; den[0] += w;
        }
        #pragma unroll
        for (int i = 1; i < 4; ++i) {
            float2 hn = hs_t[tx][ty0 + 20 + i];
            float2 ho = (i == 1) ? h0 : ((i == 2) ? h1 : h2);
            vs1 += hn.x - ho.x;
            vs2 += hn.y - ho.y;
            float a = tile[ty0 + i + PAD][tx + PAD];
            float p = tile[ty0 + i][tx];
            float dd = fmaf(a, fmaf(441.f, a, -2.f * vs1), vs2);
            float w = exp2f(dd * kE);
            num[i] += w * p; den[i] += w;
        }
    }

    // ---- epilogue: identical value for all 8 batch slices ----
    #pragma unroll
    for (int i = 0; i < 4; ++i) {
        int y = y0 + ty0 + i;
        int x = x0 + tx;
        float v = num[i] / (den[i] + 1e-10f);
        v = v < 0.f ? 0.f : (v > 1.f ? 1.f : v);
        #pragma unroll
        for (int b = 0; b < B; ++b)
            out[((size_t)(b * CCH + ch) * HH + y) * WW + x] = v;
    }
}

extern "C" void kernel_launch(void* const* d_in, const int* in_sizes, int n_in,
                              void* d_out, int out_size, void* d_ws, size_t ws_size,
                              hipStream_t stream) {
    const float* noisy = (const float*)d_in[0];
    float* out = (float*)d_out;
    dim3 grid(WW / TSX, HH / TSY, CCH);
    nlm_fused_kernel<<<grid, dim3(256), 0, stream>>>(noisy, out);
}